// Round 10
// baseline (1429.738 us; speedup 1.0000x reference)
//
#include <hip/hip_runtime.h>
#include <hip/hip_cooperative_groups.h>

namespace cg = cooperative_groups;

#define N_NODES 50000
#define MPAD    50048           // N_NODES rounded up to 128
#define IN_F    64
#define HIDDEN  512
#define N_EDGES 160000
#define N_TRAIN 80000
#define N_CLASS 7
#define BN_EPS  1e-5f

#define MT      (MPAD / 128)    // 391 m-tiles
#define NT      4               // 128-col n-tiles
#define FULLGRP ((MT / 8) * 32) // 1536: full 8-mtile x 4-ntile swizzle groups
#define NBLK    ((N_NODES + 255) / 256)   // 196 scan chunks
#define NWTASK  (32 + 5 * 256)            // wtrans tile tasks (z0:32, z1..5:256)

typedef short  bf16x8 __attribute__((ext_vector_type(8)));
typedef float  f32x4  __attribute__((ext_vector_type(4)));
typedef unsigned short ushort_t;

// ---- bf16 helpers (manual RNE; values are finite) -------------------------
__device__ __forceinline__ ushort_t f2b(float v) {
    union { float f; unsigned int u; } c; c.f = v;
    unsigned int x = c.u;
    unsigned int r = (x + 0x7FFFu + ((x >> 16) & 1u)) >> 16;
    return (ushort_t)r;
}
__device__ __forceinline__ float b2f(ushort_t b) {
    union { unsigned int u; float f; } c; c.u = ((unsigned int)b) << 16;
    return c.f;
}

// ---- async global->LDS, 16B per lane (dst = wave-uniform base + lane*16) --
__device__ __forceinline__ void async_copy16(const void* g, void* l) {
    __builtin_amdgcn_global_load_lds(
        (const __attribute__((address_space(1))) void*)g,
        (__attribute__((address_space(3))) void*)l, 16, 0, 0);
}

// ===========================================================================
// Cooperative prep kernel: CSR build (zero -> hist -> decoupled scan ->
// scatter) + weight transpose/split, all in ONE launch. wtrans overlaps the
// histogram phase (independent work). Grid 1024x256 (4 blocks/CU — safely
// co-resident for grid.sync).
// ===========================================================================
__global__ __launch_bounds__(256) void prep_coop_kernel(
    const int* __restrict__ ei,
    const float* __restrict__ W1, const float* __restrict__ W2,
    const float* __restrict__ W3, const float* __restrict__ W4,
    const float* __restrict__ W5, const float* __restrict__ W6,
    ushort_t* __restrict__ Wp,
    int* __restrict__ deg, int* __restrict__ cursor,
    int* __restrict__ rowptr, int* __restrict__ bsum,
    int* __restrict__ boff, int* __restrict__ adj) {
    cg::grid_group grid = cg::this_grid();
    const int tid = threadIdx.x, bid = blockIdx.x, NB = gridDim.x;
    const int gt = bid * 256 + tid, GS = NB * 256;
    const size_t WSMALL = (size_t)HIDDEN * IN_F;
    const size_t WBIG   = (size_t)HIDDEN * HIDDEN;

    __shared__ float twt[32][33];
    __shared__ int   sred[256];

    // ---- phase 1: zero degree array ----
    for (int i = gt; i < N_NODES; i += GS) deg[i] = 0;
    grid.sync();

    // ---- phase 2: histogram(dst) + weight transpose/split (independent) ----
    for (int e = gt; e < N_EDGES; e += GS)
        atomicAdd(&deg[ei[N_EDGES + e]], 1);

    for (int task = bid; task < NWTASK; task += NB) {
        int z, nb32, kb32;
        if (task < 32) { z = 0; nb32 = task >> 1; kb32 = task & 1; }
        else {
            int t2 = task - 32;
            z = 1 + t2 / 256;
            int rem = t2 & 255;
            nb32 = rem >> 4; kb32 = rem & 15;
        }
        const float* W = (z == 0) ? W1 : (z == 1) ? W2 : (z == 2) ? W3
                       : (z == 3) ? W4 : (z == 4) ? W5 : W6;
        int K = (z == 0) ? IN_F : HIDDEN;
        size_t off_h = (z == 0) ? 0 : 2 * WSMALL + (size_t)(z - 1) * 2 * WBIG;
        ushort_t* Whi = Wp + off_h;
        ushort_t* Wlo = Whi + ((z == 0) ? WSMALL : WBIG);

        int tx = tid & 31, ty = tid >> 5;   // ty 0..7
        int nb = nb32 * 32, kb = kb32 * 32;
        __syncthreads();
#pragma unroll
        for (int i = 0; i < 4; i++) {
            int k = kb + ty + i * 8;
            twt[ty + i * 8][tx] = W[(size_t)k * HIDDEN + nb + tx];
        }
        __syncthreads();
#pragma unroll
        for (int i = 0; i < 4; i++) {
            int n = nb + ty + i * 8;
            int k = kb + tx;
            float v = twt[tx][ty + i * 8];
            ushort_t hb = f2b(v);
            ushort_t lb = f2b(v - b2f(hb));
            Whi[(size_t)n * K + k] = hb;
            Wlo[(size_t)n * K + k] = lb;
        }
    }
    grid.sync();

    // ---- phase 3: per-256-chunk sums ----
    for (int c = bid; c < NBLK; c += NB) {
        __syncthreads();
        int i = c * 256 + tid;
        sred[tid] = (i < N_NODES) ? deg[i] : 0;
        __syncthreads();
        for (int off = 128; off > 0; off >>= 1) {
            if (tid < off) sred[tid] += sred[tid + off];
            __syncthreads();
        }
        if (tid == 0) bsum[c] = sred[0];
    }
    grid.sync();

    // ---- phase 4: exclusive scan of chunk sums (block 0 only) ----
    if (bid == 0) {
        sred[tid] = (tid < NBLK) ? bsum[tid] : 0;
        __syncthreads();
        for (int off = 1; off < 256; off <<= 1) {
            int t = (tid >= off) ? sred[tid - off] : 0;
            __syncthreads();
            sred[tid] += t;
            __syncthreads();
        }
        if (tid < NBLK) boff[tid] = (tid == 0) ? 0 : sred[tid - 1];
    }
    grid.sync();

    // ---- phase 5: rowptr + scatter cursor ----
    for (int c = bid; c < NBLK; c += NB) {
        __syncthreads();
        int i = c * 256 + tid;
        int d = (i < N_NODES) ? deg[i] : 0;
        sred[tid] = d;
        __syncthreads();
        for (int off = 1; off < 256; off <<= 1) {
            int t = (tid >= off) ? sred[tid - off] : 0;
            __syncthreads();
            sred[tid] += t;
            __syncthreads();
        }
        int incl = sred[tid] + boff[c];
        if (i < N_NODES) {
            rowptr[i + 1] = incl;
            cursor[i] = incl - d;
        }
    }
    if (gt == 0) rowptr[0] = 0;
    grid.sync();

    // ---- phase 6: scatter src ids ----
    for (int e = gt; e < N_EDGES; e += GS) {
        int src = ei[e], dst = ei[N_EDGES + e];
        int pos = atomicAdd(&cursor[dst], 1);
        adj[pos] = src;
    }
}

// ===========================================================================
// Gather aggregation (CSR), fused scale + split-bf16 output.
// out[n] = (1+eps)*h[n] + sum_{k in row n} h[adj[k]]
// ===========================================================================
__global__ __launch_bounds__(256) void gather64_kernel(
    const float* __restrict__ x, const int* __restrict__ rowptr,
    const int* __restrict__ adj, const float* __restrict__ epsp,
    ushort_t* __restrict__ hi, ushort_t* __restrict__ lo) {
    int wave = threadIdx.x >> 6, lane = threadIdx.x & 63;
    int n = blockIdx.x * 4 + wave;
    if (n >= N_NODES) return;
    float s = 1.0f + *epsp;
    float sum = s * x[(size_t)n * IN_F + lane];
    int beg = rowptr[n], end = rowptr[n + 1];
    for (int k = beg; k < end; k++) {
        sum += x[(size_t)adj[k] * IN_F + lane];
    }
    ushort_t hb = f2b(sum);
    ushort_t lb = f2b(sum - b2f(hb));
    hi[(size_t)n * IN_F + lane] = hb;
    lo[(size_t)n * IN_F + lane] = lb;
}

// 2 waves per node (256 features each)
__global__ __launch_bounds__(256) void gather512_kernel(
    const float* __restrict__ h, const int* __restrict__ rowptr,
    const int* __restrict__ adj, const float* __restrict__ epsp,
    ushort_t* __restrict__ hi, ushort_t* __restrict__ lo) {
    int wave = threadIdx.x >> 6, lane = threadIdx.x & 63;
    int n = blockIdx.x * 2 + (wave >> 1);
    if (n >= N_NODES) return;
    float s = 1.0f + *epsp;
    const int f = (wave & 1) * 256 + lane * 4;
    float4 a = *(const float4*)&h[(size_t)n * HIDDEN + f];
    float sum[4] = {s * a.x, s * a.y, s * a.z, s * a.w};
    int beg = rowptr[n], end = rowptr[n + 1];
    for (int k = beg; k < end; k++) {
        float4 b = *(const float4*)&h[(size_t)adj[k] * HIDDEN + f];
        sum[0] += b.x; sum[1] += b.y; sum[2] += b.z; sum[3] += b.w;
    }
    ushort_t h4[4], l4[4];
#pragma unroll
    for (int j = 0; j < 4; j++) {
        h4[j] = f2b(sum[j]);
        l4[j] = f2b(sum[j] - b2f(h4[j]));
    }
    *(ushort4*)&hi[(size_t)n * HIDDEN + f] = make_ushort4(h4[0], h4[1], h4[2], h4[3]);
    *(ushort4*)&lo[(size_t)n * HIDDEN + f] = make_ushort4(l4[0], l4[1], l4[2], l4[3]);
}

// ---------------------------------------------------------------------------
// Split-bf16 MFMA GEMM (K=512): single-buffer LDS + verified swizzle.
// FROZEN at the measured structural plateau (R5-R8: no-LDS and dbuf both
// regressed; swizzle zeroed conflicts).
// ---------------------------------------------------------------------------
template<int K>
__global__ __launch_bounds__(256) void gemm_split_kernel(
    const ushort_t* __restrict__ Ahi, const ushort_t* __restrict__ Alo,
    const ushort_t* __restrict__ Bhi, const ushort_t* __restrict__ Blo,
    const float* __restrict__ bias,
    float* __restrict__ Cf, ushort_t* __restrict__ Chi, ushort_t* __restrict__ Clo,
    int mode,
    const float* __restrict__ bn_g, const float* __restrict__ bn_b,
    const float* __restrict__ bn_m, const float* __restrict__ bn_v) {
    __shared__ ushort_t As_h[128 * 32];
    __shared__ ushort_t As_l[128 * 32];
    __shared__ ushort_t Bs_h[128 * 32];
    __shared__ ushort_t Bs_l[128 * 32];

    const int tid  = threadIdx.x;
    const int wave = tid >> 6, lane = tid & 63;
    const int wm = wave >> 1, wn = wave & 1;
    const int quad = lane >> 4, r = lane & 15;

    int idx = blockIdx.x, m_t, n_t;
    if (idx < FULLGRP) {
        m_t = (idx >> 5) * 8 + (idx & 7);
        n_t = (idx >> 3) & 3;
    } else {
        int t = idx - FULLGRP;
        m_t = (FULLGRP >> 2) + (t >> 2);
        n_t = t & 3;
    }
    const int m0 = m_t * 128, n0 = n_t * 128;

    const f32x4 vzero = {0.f, 0.f, 0.f, 0.f};
    f32x4 acc[4][4];
#pragma unroll
    for (int i = 0; i < 4; i++)
#pragma unroll
        for (int j = 0; j < 4; j++) acc[i][j] = vzero;

    const int srow = lane >> 2;
    const int scol = (((lane & 3) + ((srow >> 1) & 3)) & 3) * 8;
    const int csw  = ((quad - ((r >> 1) & 3)) & 3) * 8;

    for (int k0 = 0; k0 < K; k0 += 32) {
        __syncthreads();
#pragma unroll
        for (int tt = 0; tt < 2; tt++) {
            int rr = wave * 32 + tt * 16 + srow;
            int lbase = (wave * 32 + tt * 16) * 32;
            size_t ga = (size_t)(m0 + rr) * K + k0 + scol;
            size_t gb = (size_t)(n0 + rr) * K + k0 + scol;
            async_copy16(Ahi + ga, &As_h[lbase]);
            async_copy16(Alo + ga, &As_l[lbase]);
            async_copy16(Bhi + gb, &Bs_h[lbase]);
            async_copy16(Blo + gb, &Bs_l[lbase]);
        }
        __syncthreads();

        bf16x8 ah[4], al[4], bh[4], bl[4];
#pragma unroll
        for (int i = 0; i < 4; i++) {
            int aofs = (wm * 64 + i * 16 + r) * 32 + csw;
            int bofs = (wn * 64 + i * 16 + r) * 32 + csw;
            ah[i] = *(const bf16x8*)&As_h[aofs];
            al[i] = *(const bf16x8*)&As_l[aofs];
            bh[i] = *(const bf16x8*)&Bs_h[bofs];
            bl[i] = *(const bf16x8*)&Bs_l[bofs];
        }
#pragma unroll
        for (int i = 0; i < 4; i++)
#pragma unroll
            for (int j = 0; j < 4; j++) {
                acc[i][j] = __builtin_amdgcn_mfma_f32_16x16x32_bf16(ah[i], bh[j], acc[i][j], 0, 0, 0);
                acc[i][j] = __builtin_amdgcn_mfma_f32_16x16x32_bf16(ah[i], bl[j], acc[i][j], 0, 0, 0);
                acc[i][j] = __builtin_amdgcn_mfma_f32_16x16x32_bf16(al[i], bh[j], acc[i][j], 0, 0, 0);
            }
    }

    float bia[4], sc[4], sh[4];
#pragma unroll
    for (int j = 0; j < 4; j++) {
        int col = n0 + wn * 64 + j * 16 + r;
        bia[j] = bias[col];
        if (mode == 2) {
            float g = bn_g[col], bb = bn_b[col], mm = bn_m[col], vv = bn_v[col];
            sc[j] = g * rsqrtf(vv + BN_EPS);
            sh[j] = bb - mm * sc[j];
        } else { sc[j] = 1.f; sh[j] = 0.f; }
    }
#pragma unroll
    for (int i = 0; i < 4; i++) {
#pragma unroll
        for (int rg = 0; rg < 4; rg++) {
            int row = m0 + wm * 64 + i * 16 + quad * 4 + rg;
            if (row >= N_NODES) continue;
#pragma unroll
            for (int j = 0; j < 4; j++) {
                int col = n0 + wn * 64 + j * 16 + r;
                float v = acc[i][j][rg] + bia[j];
                if (mode >= 1) v = fmaxf(v, 0.f);
                if (mode == 2) v = v * sc[j] + sh[j];
                size_t oix = (size_t)row * HIDDEN + col;
                if (Cf) {
                    Cf[oix] = v;
                } else {
                    ushort_t hb = f2b(v);
                    ushort_t lb = f2b(v - b2f(hb));
                    Chi[oix] = hb;
                    Clo[oix] = lb;
                }
            }
        }
    }
}

// ---------------------------------------------------------------------------
// K=64 specialized GEMM: whole K staged once in 64 KB LDS, ONE barrier total.
// ---------------------------------------------------------------------------
__global__ __launch_bounds__(256) void gemm_k64_kernel(
    const ushort_t* __restrict__ Ahi, const ushort_t* __restrict__ Alo,
    const ushort_t* __restrict__ Bhi, const ushort_t* __restrict__ Blo,
    const float* __restrict__ bias,
    ushort_t* __restrict__ Chi, ushort_t* __restrict__ Clo) {
    const int K = 64;
    __shared__ ushort_t As_h[128 * 64];
    __shared__ ushort_t As_l[128 * 64];
    __shared__ ushort_t Bs_h[128 * 64];
    __shared__ ushort_t Bs_l[128 * 64];

    const int tid  = threadIdx.x;
    const int wave = tid >> 6, lane = tid & 63;
    const int wm = wave >> 1, wn = wave & 1;
    const int quad = lane >> 4, r = lane & 15;

    int idx = blockIdx.x, m_t, n_t;
    if (idx < FULLGRP) {
        m_t = (idx >> 5) * 8 + (idx & 7);
        n_t = (idx >> 3) & 3;
    } else {
        int t = idx - FULLGRP;
        m_t = (FULLGRP >> 2) + (t >> 2);
        n_t = t & 3;
    }
    const int m0 = m_t * 128, n0 = n_t * 128;

    const int srow8 = lane >> 3;                       // 0..7
    const int sc8   = (((lane & 7) - srow8) & 7) * 8;  // src elem offset
#pragma unroll
    for (int t = 0; t < 4; t++) {
        int base = wave * 32 + t * 8;
        int rr = base + srow8;
        int lbase = base * 64;
        size_t ga = (size_t)(m0 + rr) * K + sc8;
        size_t gb = (size_t)(n0 + rr) * K + sc8;
        async_copy16(Ahi + ga, &As_h[lbase]);
        async_copy16(Alo + ga, &As_l[lbase]);
        async_copy16(Bhi + gb, &Bs_h[lbase]);
        async_copy16(Blo + gb, &Bs_l[lbase]);
    }
    __syncthreads();

    const f32x4 vzero = {0.f, 0.f, 0.f, 0.f};
    f32x4 acc[4][4];
#pragma unroll
    for (int i = 0; i < 4; i++)
#pragma unroll
        for (int j = 0; j < 4; j++) acc[i][j] = vzero;

#pragma unroll
    for (int ks = 0; ks < 2; ks++) {
        bf16x8 ah[4], al[4], bh[4], bl[4];
#pragma unroll
        for (int i = 0; i < 4; i++) {
            int ra = wm * 64 + i * 16 + r;
            int rb = wn * 64 + i * 16 + r;
            int ca = ((quad + ks * 4 + (ra & 7)) & 7) * 8;
            int cb = ((quad + ks * 4 + (rb & 7)) & 7) * 8;
            ah[i] = *(const bf16x8*)&As_h[ra * 64 + ca];
            al[i] = *(const bf16x8*)&As_l[ra * 64 + ca];
            bh[i] = *(const bf16x8*)&Bs_h[rb * 64 + cb];
            bl[i] = *(const bf16x8*)&Bs_l[rb * 64 + cb];
        }
#pragma unroll
        for (int i = 0; i < 4; i++)
#pragma unroll
            for (int j = 0; j < 4; j++) {
                acc[i][j] = __builtin_amdgcn_mfma_f32_16x16x32_bf16(ah[i], bh[j], acc[i][j], 0, 0, 0);
                acc[i][j] = __builtin_amdgcn_mfma_f32_16x16x32_bf16(ah[i], bl[j], acc[i][j], 0, 0, 0);
                acc[i][j] = __builtin_amdgcn_mfma_f32_16x16x32_bf16(al[i], bh[j], acc[i][j], 0, 0, 0);
            }
    }

    float bia[4];
#pragma unroll
    for (int j = 0; j < 4; j++) bia[j] = bias[n0 + wn * 64 + j * 16 + r];
#pragma unroll
    for (int i = 0; i < 4; i++) {
#pragma unroll
        for (int rg = 0; rg < 4; rg++) {
            int row = m0 + wm * 64 + i * 16 + quad * 4 + rg;
            if (row >= N_NODES) continue;
#pragma unroll
            for (int j = 0; j < 4; j++) {
                int col = n0 + wn * 64 + j * 16 + r;
                float v = fmaxf(acc[i][j][rg] + bia[j], 0.f);
                size_t oix = (size_t)row * HIDDEN + col;
                ushort_t hb = f2b(v);
                ushort_t lb = f2b(v - b2f(hb));
                Chi[oix] = hb;
                Clo[oix] = lb;
            }
        }
    }
}

// ---------------------------------------------------------------------------
// out[t] = (h[a_t] * h[b_t]) @ fc2_W + fc2_b ; one wave per train edge.
// ---------------------------------------------------------------------------
__global__ __launch_bounds__(256) void fc2_kernel(
    const float* __restrict__ h, const int* __restrict__ ei,
    const int* __restrict__ teid, const float* __restrict__ W,
    const float* __restrict__ bias, float* __restrict__ out) {
    __shared__ float Ws[HIDDEN * N_CLASS];
    __shared__ float bs[N_CLASS];
    for (int i = threadIdx.x; i < HIDDEN * N_CLASS; i += blockDim.x) Ws[i] = W[i];
    if (threadIdx.x < N_CLASS) bs[threadIdx.x] = bias[threadIdx.x];
    __syncthreads();

    int wave = threadIdx.x >> 6;
    int lane = threadIdx.x & 63;
    int t = blockIdx.x * 4 + wave;
    if (t >= N_TRAIN) return;

    int e = teid[t];
    int a = ei[e];
    int b = ei[N_EDGES + e];
    const float* xa = h + (size_t)a * HIDDEN;
    const float* xb = h + (size_t)b * HIDDEN;

    float acc[N_CLASS];
#pragma unroll
    for (int c = 0; c < N_CLASS; c++) acc[c] = 0.f;

    int j0 = lane * 8;
    float4 a0 = *(const float4*)&xa[j0];
    float4 a1 = *(const float4*)&xa[j0 + 4];
    float4 b0 = *(const float4*)&xb[j0];
    float4 b1 = *(const float4*)&xb[j0 + 4];
    float p[8] = {a0.x * b0.x, a0.y * b0.y, a0.z * b0.z, a0.w * b0.w,
                  a1.x * b1.x, a1.y * b1.y, a1.z * b1.z, a1.w * b1.w};
#pragma unroll
    for (int jj = 0; jj < 8; jj++) {
        const float* wrow = &Ws[(j0 + jj) * N_CLASS];
#pragma unroll
        for (int c = 0; c < N_CLASS; c++) acc[c] = fmaf(p[jj], wrow[c], acc[c]);
    }
#pragma unroll
    for (int c = 0; c < N_CLASS; c++) {
        float v = acc[c];
        for (int off = 32; off > 0; off >>= 1) v += __shfl_down(v, off, 64);
        if (lane == 0) out[(size_t)t * N_CLASS + c] = v + bs[c];
    }
}

// ---------------------------------------------------------------------------
extern "C" void kernel_launch(void* const* d_in, const int* in_sizes, int n_in,
                              void* d_out, int out_size, void* d_ws, size_t ws_size,
                              hipStream_t stream) {
    const float* x      = (const float*)d_in[0];
    const int*   ei     = (const int*)d_in[1];
    const int*   teid   = (const int*)d_in[2];
    const float* W1     = (const float*)d_in[3];
    const float* b1     = (const float*)d_in[4];
    const float* W2     = (const float*)d_in[5];
    const float* b2     = (const float*)d_in[6];
    const float* W3     = (const float*)d_in[7];
    const float* b3     = (const float*)d_in[8];
    const float* bn1_g  = (const float*)d_in[9];
    const float* bn1_b  = (const float*)d_in[10];
    const float* bn1_m  = (const float*)d_in[11];
    const float* bn1_v  = (const float*)d_in[12];
    const float* eps1   = (const float*)d_in[13];
    const float* W4     = (const float*)d_in[14];
    const float* b4     = (const float*)d_in[15];
    const float* bn2_g  = (const float*)d_in[16];
    const float* bn2_b  = (const float*)d_in[17];
    const float* bn2_m  = (const float*)d_in[18];
    const float* bn2_v  = (const float*)d_in[19];
    const float* eps2   = (const float*)d_in[20];
    const float* lin1_W = (const float*)d_in[21];
    const float* lin1_b = (const float*)d_in[22];
    const float* lin2_W = (const float*)d_in[23];
    const float* lin2_b = (const float*)d_in[24];
    const float* fc2_W  = (const float*)d_in[25];
    const float* fc2_b  = (const float*)d_in[26];

    const size_t PLANE   = (size_t)MPAD * HIDDEN;
    const size_t PLANE64 = (size_t)MPAD * IN_F;

    ushort_t* R0h = (ushort_t*)d_ws;
    ushort_t* R0l = R0h + PLANE;
    ushort_t* R1h = R0l + PLANE;
    ushort_t* R1l = R1h + PLANE;

    const size_t WSMALL = (size_t)HIDDEN * IN_F;
    const size_t WBIG   = (size_t)HIDDEN * HIDDEN;
    ushort_t* Wp   = R1l + PLANE;
    ushort_t* Wt1h = Wp;            ushort_t* Wt1l = Wt1h + WSMALL;
    ushort_t* Wt2h = Wt1l + WSMALL; ushort_t* Wt2l = Wt2h + WBIG;
    ushort_t* Wt3h = Wt2l + WBIG;   ushort_t* Wt3l = Wt3h + WBIG;
    ushort_t* Wt4h = Wt3l + WBIG;   ushort_t* Wt4l = Wt4h + WBIG;
    ushort_t* Wt5h = Wt4l + WBIG;   ushort_t* Wt5l = Wt5h + WBIG;
    ushort_t* Wt6h = Wt5l + WBIG;   ushort_t* Wt6l = Wt6h + WBIG;

    // CSR arrays (ints) after weights
    int* deg    = (int*)(Wt6l + WBIG);
    int* cursor = deg + N_NODES;
    int* rowptr = cursor + N_NODES;        // N_NODES + 1
    int* bsum   = rowptr + (N_NODES + 1);  // NBLK
    int* boff   = bsum + NBLK;             // NBLK
    int* adj    = boff + NBLK;             // N_EDGES

    // fp32 aliases
    float* F32_R0 = (float*)R0h;
    ushort_t* H0h = R1h;
    ushort_t* H0l = R1h + PLANE64;

    // ---- fused prep: CSR build + weight transpose/split (1 coop launch) ----
    {
        void* cargs[] = {(void*)&ei, (void*)&W1, (void*)&W2, (void*)&W3,
                         (void*)&W4, (void*)&lin1_W, (void*)&lin2_W, (void*)&Wp,
                         (void*)&deg, (void*)&cursor, (void*)&rowptr,
                         (void*)&bsum, (void*)&boff, (void*)&adj};
        hipLaunchCooperativeKernel((void*)prep_coop_kernel, dim3(1024), dim3(256),
                                   cargs, 0, stream);
    }

    const int ngrid = MT * NT;     // 1564 blocks, 1-D swizzled grid
    int nwb = (N_NODES + 3) / 4;

    // ---- h0 = (1+eps1)*x + gather(x) -> H0 split ----
    gather64_kernel<<<nwb, 256, 0, stream>>>(x, rowptr, adj, eps1, H0h, H0l);

    // h1 = relu(h0 @ W1 + b1) -> R0 split  (K=64 single-stage kernel)
    gemm_k64_kernel<<<ngrid, 256, 0, stream>>>(H0h, H0l, Wt1h, Wt1l, b1, R0h, R0l);
    // h2 = relu(h1 @ W2 + b2) -> R1 split
    gemm_split_kernel<HIDDEN><<<ngrid, 256, 0, stream>>>(R0h, R0l, Wt2h, Wt2l, b2,
        nullptr, R1h, R1l, 1, nullptr, nullptr, nullptr, nullptr);
    // h3 = bn1(relu(h2 @ W3 + b3)) -> F32_R0
    gemm_split_kernel<HIDDEN><<<ngrid, 256, 0, stream>>>(R1h, R1l, Wt3h, Wt3l, b3,
        F32_R0, nullptr, nullptr, 2, bn1_g, bn1_b, bn1_m, bn1_v);

    // ---- h4 = (1+eps2)*h3 + gather(h3) -> R1 split (2 waves/node) ----
    gather512_kernel<<<(N_NODES + 1) / 2, 256, 0, stream>>>(F32_R0, rowptr, adj,
                                                            eps2, R1h, R1l);

    // h5 = bn2(relu(h4 @ W4 + b4)) -> R0 split
    gemm_split_kernel<HIDDEN><<<ngrid, 256, 0, stream>>>(R1h, R1l, Wt4h, Wt4l, b4,
        nullptr, R0h, R0l, 2, bn2_g, bn2_b, bn2_m, bn2_v);
    // h6 = relu(h5 @ lin1_W + lin1_b) -> R1 split
    gemm_split_kernel<HIDDEN><<<ngrid, 256, 0, stream>>>(R0h, R0l, Wt5h, Wt5l, lin1_b,
        nullptr, R1h, R1l, 1, nullptr, nullptr, nullptr, nullptr);
    // h7 = h6 @ lin2_W + lin2_b -> F32_R0
    gemm_split_kernel<HIDDEN><<<ngrid, 256, 0, stream>>>(R1h, R1l, Wt6h, Wt6l, lin2_b,
        F32_R0, nullptr, nullptr, 0, nullptr, nullptr, nullptr, nullptr);

    // head
    fc2_kernel<<<(N_TRAIN + 3) / 4, 256, 0, stream>>>(F32_R0, ei, teid, fc2_W, fc2_b,
                                                      (float*)d_out);
}

// Round 11
// 958.629 us; speedup vs baseline: 1.4914x; 1.4914x over previous
//
#include <hip/hip_runtime.h>

#define N_NODES 50000
#define MPAD    50048           // N_NODES rounded up to 128
#define IN_F    64
#define HIDDEN  512
#define N_EDGES 160000
#define N_TRAIN 80000
#define N_CLASS 7
#define BN_EPS  1e-5f

#define MT      (MPAD / 128)    // 391 m-tiles
#define NT      4               // 128-col n-tiles
#define FULLGRP ((MT / 8) * 32) // 1536: full 8-mtile x 4-ntile swizzle groups
#define NBLK    ((N_NODES + 255) / 256)   // 196 scan blocks

typedef short  bf16x8 __attribute__((ext_vector_type(8)));
typedef float  f32x4  __attribute__((ext_vector_type(4)));
typedef unsigned short ushort_t;

// ---- bf16 helpers (manual RNE; values are finite) -------------------------
__device__ __forceinline__ ushort_t f2b(float v) {
    union { float f; unsigned int u; } c; c.f = v;
    unsigned int x = c.u;
    unsigned int r = (x + 0x7FFFu + ((x >> 16) & 1u)) >> 16;
    return (ushort_t)r;
}
__device__ __forceinline__ float b2f(ushort_t b) {
    union { unsigned int u; float f; } c; c.u = ((unsigned int)b) << 16;
    return c.f;
}

// ---- async global->LDS, 16B per lane (dst = wave-uniform base + lane*16) --
__device__ __forceinline__ void async_copy16(const void* g, void* l) {
    __builtin_amdgcn_global_load_lds(
        (const __attribute__((address_space(1))) void*)g,
        (__attribute__((address_space(3))) void*)l, 16, 0, 0);
}

// ===========================================================================
// CSR build: zero -> histogram(dst) -> decoupled scan -> scatter src ids.
// Separate small launches: R10 showed grid.sync() costs ~80 µs/sync on this
// stack — a chain of tiny ordinary launches is an order of magnitude cheaper.
// ===========================================================================
__global__ void zero_kernel(int* __restrict__ p, int n) {
    int i = blockIdx.x * blockDim.x + threadIdx.x;
    if (i < n) p[i] = 0;
}

__global__ void hist_kernel(const int* __restrict__ ei, int* __restrict__ deg) {
    int e = blockIdx.x * blockDim.x + threadIdx.x;
    if (e >= N_EDGES) return;
    atomicAdd(&deg[ei[N_EDGES + e]], 1);
}

// per-256-chunk sums of deg
__global__ __launch_bounds__(256) void blocksum_kernel(const int* __restrict__ deg,
                                                       int* __restrict__ bsum) {
    __shared__ int s[256];
    int i = blockIdx.x * 256 + threadIdx.x;
    s[threadIdx.x] = (i < N_NODES) ? deg[i] : 0;
    __syncthreads();
    for (int off = 128; off > 0; off >>= 1) {
        if (threadIdx.x < off) s[threadIdx.x] += s[threadIdx.x + off];
        __syncthreads();
    }
    if (threadIdx.x == 0) bsum[blockIdx.x] = s[0];
}

// single block: exclusive scan of NBLK(=196) block sums
__global__ __launch_bounds__(256) void scanbsum_kernel(const int* __restrict__ bsum,
                                                       int* __restrict__ boff) {
    __shared__ int s[256];
    int tid = threadIdx.x;
    s[tid] = (tid < NBLK) ? bsum[tid] : 0;
    __syncthreads();
    for (int off = 1; off < 256; off <<= 1) {
        int t = (tid >= off) ? s[tid - off] : 0;
        __syncthreads();
        s[tid] += t;
        __syncthreads();
    }
    if (tid < NBLK) boff[tid] = (tid == 0) ? 0 : s[tid - 1];
}

// per-block local inclusive scan + block offset -> rowptr and scatter cursor
__global__ __launch_bounds__(256) void rowptr_kernel(const int* __restrict__ deg,
                                                     const int* __restrict__ boff,
                                                     int* __restrict__ rowptr,
                                                     int* __restrict__ cursor) {
    __shared__ int s[256];
    int tid = threadIdx.x;
    int i = blockIdx.x * 256 + tid;
    int d = (i < N_NODES) ? deg[i] : 0;
    s[tid] = d;
    __syncthreads();
    for (int off = 1; off < 256; off <<= 1) {
        int t = (tid >= off) ? s[tid - off] : 0;
        __syncthreads();
        s[tid] += t;
        __syncthreads();
    }
    int incl = s[tid] + boff[blockIdx.x];
    if (i < N_NODES) {
        rowptr[i + 1] = incl;
        cursor[i] = incl - d;   // exclusive prefix = row start
    }
    if (i == 0) rowptr[0] = 0;
}

__global__ void scatter_kernel(const int* __restrict__ ei,
                               int* __restrict__ cursor, int* __restrict__ adj) {
    int e = blockIdx.x * blockDim.x + threadIdx.x;
    if (e >= N_EDGES) return;
    int src = ei[e], dst = ei[N_EDGES + e];
    int pos = atomicAdd(&cursor[dst], 1);
    adj[pos] = src;
}

// ===========================================================================
// Gather aggregation (CSR), fused scale + split-bf16 output.
// out[n] = (1+eps)*h[n] + sum_{k in row n} h[adj[k]]
// ===========================================================================
__global__ __launch_bounds__(256) void gather64_kernel(
    const float* __restrict__ x, const int* __restrict__ rowptr,
    const int* __restrict__ adj, const float* __restrict__ epsp,
    ushort_t* __restrict__ hi, ushort_t* __restrict__ lo) {
    int wave = threadIdx.x >> 6, lane = threadIdx.x & 63;
    int n = blockIdx.x * 4 + wave;
    if (n >= N_NODES) return;
    float s = 1.0f + *epsp;
    float sum = s * x[(size_t)n * IN_F + lane];
    int beg = rowptr[n], end = rowptr[n + 1];
    for (int k = beg; k < end; k++) {
        sum += x[(size_t)adj[k] * IN_F + lane];
    }
    ushort_t hb = f2b(sum);
    ushort_t lb = f2b(sum - b2f(hb));
    hi[(size_t)n * IN_F + lane] = hb;
    lo[(size_t)n * IN_F + lane] = lb;
}

// 2 waves per node (256 features each)
__global__ __launch_bounds__(256) void gather512_kernel(
    const float* __restrict__ h, const int* __restrict__ rowptr,
    const int* __restrict__ adj, const float* __restrict__ epsp,
    ushort_t* __restrict__ hi, ushort_t* __restrict__ lo) {
    int wave = threadIdx.x >> 6, lane = threadIdx.x & 63;
    int n = blockIdx.x * 2 + (wave >> 1);
    if (n >= N_NODES) return;
    float s = 1.0f + *epsp;
    const int f = (wave & 1) * 256 + lane * 4;
    float4 a = *(const float4*)&h[(size_t)n * HIDDEN + f];
    float sum[4] = {s * a.x, s * a.y, s * a.z, s * a.w};
    int beg = rowptr[n], end = rowptr[n + 1];
    for (int k = beg; k < end; k++) {
        float4 b = *(const float4*)&h[(size_t)adj[k] * HIDDEN + f];
        sum[0] += b.x; sum[1] += b.y; sum[2] += b.z; sum[3] += b.w;
    }
    ushort_t h4[4], l4[4];
#pragma unroll
    for (int j = 0; j < 4; j++) {
        h4[j] = f2b(sum[j]);
        l4[j] = f2b(sum[j] - b2f(h4[j]));
    }
    *(ushort4*)&hi[(size_t)n * HIDDEN + f] = make_ushort4(h4[0], h4[1], h4[2], h4[3]);
    *(ushort4*)&lo[(size_t)n * HIDDEN + f] = make_ushort4(l4[0], l4[1], l4[2], l4[3]);
}

// ---------------------------------------------------------------------------
// Batched weight prep: all 6 W[K][512] fp32 -> Wt_hi/lo[512][K] bf16.
// grid (16, 16, 6); z selects weight; z=0 has K=64 (extra kb blocks exit).
// ---------------------------------------------------------------------------
__global__ void wtrans_all_kernel(const float* __restrict__ w0,
                                  const float* __restrict__ w1,
                                  const float* __restrict__ w2,
                                  const float* __restrict__ w3,
                                  const float* __restrict__ w4,
                                  const float* __restrict__ w5,
                                  ushort_t* __restrict__ Wp) {
    const size_t WSMALL = (size_t)HIDDEN * IN_F;
    const size_t WBIG   = (size_t)HIDDEN * HIDDEN;
    int z = blockIdx.z;
    const float* W = (z == 0) ? w0 : (z == 1) ? w1 : (z == 2) ? w2
                   : (z == 3) ? w3 : (z == 4) ? w4 : w5;
    int K = (z == 0) ? IN_F : HIDDEN;
    size_t off_h = (z == 0) ? 0 : 2 * WSMALL + (size_t)(z - 1) * 2 * WBIG;
    ushort_t* Whi = Wp + off_h;
    ushort_t* Wlo = Whi + ((z == 0) ? WSMALL : WBIG);

    __shared__ float t[32][33];
    int tx = threadIdx.x & 31, ty = threadIdx.x >> 5;   // ty 0..7
    int nb = blockIdx.x * 32, kb = blockIdx.y * 32;
    if (kb >= K) return;
#pragma unroll
    for (int i = 0; i < 4; i++) {
        int k = kb + ty + i * 8;
        t[ty + i * 8][tx] = W[(size_t)k * HIDDEN + nb + tx];
    }
    __syncthreads();
#pragma unroll
    for (int i = 0; i < 4; i++) {
        int n = nb + ty + i * 8;
        int k = kb + tx;
        float v = t[tx][ty + i * 8];
        ushort_t hb = f2b(v);
        ushort_t lb = f2b(v - b2f(hb));
        Whi[(size_t)n * K + k] = hb;
        Wlo[(size_t)n * K + k] = lb;
    }
}

// ---------------------------------------------------------------------------
// Split-bf16 MFMA GEMM (K=512): single-buffer LDS + verified swizzle.
// FROZEN at the measured structural plateau (R5-R8: no-LDS and dbuf both
// regressed; swizzle zeroed conflicts).
// ---------------------------------------------------------------------------
template<int K>
__global__ __launch_bounds__(256) void gemm_split_kernel(
    const ushort_t* __restrict__ Ahi, const ushort_t* __restrict__ Alo,
    const ushort_t* __restrict__ Bhi, const ushort_t* __restrict__ Blo,
    const float* __restrict__ bias,
    float* __restrict__ Cf, ushort_t* __restrict__ Chi, ushort_t* __restrict__ Clo,
    int mode,
    const float* __restrict__ bn_g, const float* __restrict__ bn_b,
    const float* __restrict__ bn_m, const float* __restrict__ bn_v) {
    __shared__ ushort_t As_h[128 * 32];
    __shared__ ushort_t As_l[128 * 32];
    __shared__ ushort_t Bs_h[128 * 32];
    __shared__ ushort_t Bs_l[128 * 32];

    const int tid  = threadIdx.x;
    const int wave = tid >> 6, lane = tid & 63;
    const int wm = wave >> 1, wn = wave & 1;
    const int quad = lane >> 4, r = lane & 15;

    int idx = blockIdx.x, m_t, n_t;
    if (idx < FULLGRP) {
        m_t = (idx >> 5) * 8 + (idx & 7);
        n_t = (idx >> 3) & 3;
    } else {
        int t = idx - FULLGRP;
        m_t = (FULLGRP >> 2) + (t >> 2);
        n_t = t & 3;
    }
    const int m0 = m_t * 128, n0 = n_t * 128;

    const f32x4 vzero = {0.f, 0.f, 0.f, 0.f};
    f32x4 acc[4][4];
#pragma unroll
    for (int i = 0; i < 4; i++)
#pragma unroll
        for (int j = 0; j < 4; j++) acc[i][j] = vzero;

    const int srow = lane >> 2;
    const int scol = (((lane & 3) + ((srow >> 1) & 3)) & 3) * 8;
    const int csw  = ((quad - ((r >> 1) & 3)) & 3) * 8;

    for (int k0 = 0; k0 < K; k0 += 32) {
        __syncthreads();
#pragma unroll
        for (int tt = 0; tt < 2; tt++) {
            int rr = wave * 32 + tt * 16 + srow;
            int lbase = (wave * 32 + tt * 16) * 32;
            size_t ga = (size_t)(m0 + rr) * K + k0 + scol;
            size_t gb = (size_t)(n0 + rr) * K + k0 + scol;
            async_copy16(Ahi + ga, &As_h[lbase]);
            async_copy16(Alo + ga, &As_l[lbase]);
            async_copy16(Bhi + gb, &Bs_h[lbase]);
            async_copy16(Blo + gb, &Bs_l[lbase]);
        }
        __syncthreads();

        bf16x8 ah[4], al[4], bh[4], bl[4];
#pragma unroll
        for (int i = 0; i < 4; i++) {
            int aofs = (wm * 64 + i * 16 + r) * 32 + csw;
            int bofs = (wn * 64 + i * 16 + r) * 32 + csw;
            ah[i] = *(const bf16x8*)&As_h[aofs];
            al[i] = *(const bf16x8*)&As_l[aofs];
            bh[i] = *(const bf16x8*)&Bs_h[bofs];
            bl[i] = *(const bf16x8*)&Bs_l[bofs];
        }
#pragma unroll
        for (int i = 0; i < 4; i++)
#pragma unroll
            for (int j = 0; j < 4; j++) {
                acc[i][j] = __builtin_amdgcn_mfma_f32_16x16x32_bf16(ah[i], bh[j], acc[i][j], 0, 0, 0);
                acc[i][j] = __builtin_amdgcn_mfma_f32_16x16x32_bf16(ah[i], bl[j], acc[i][j], 0, 0, 0);
                acc[i][j] = __builtin_amdgcn_mfma_f32_16x16x32_bf16(al[i], bh[j], acc[i][j], 0, 0, 0);
            }
    }

    float bia[4], sc[4], sh[4];
#pragma unroll
    for (int j = 0; j < 4; j++) {
        int col = n0 + wn * 64 + j * 16 + r;
        bia[j] = bias[col];
        if (mode == 2) {
            float g = bn_g[col], bb = bn_b[col], mm = bn_m[col], vv = bn_v[col];
            sc[j] = g * rsqrtf(vv + BN_EPS);
            sh[j] = bb - mm * sc[j];
        } else { sc[j] = 1.f; sh[j] = 0.f; }
    }
#pragma unroll
    for (int i = 0; i < 4; i++) {
#pragma unroll
        for (int rg = 0; rg < 4; rg++) {
            int row = m0 + wm * 64 + i * 16 + quad * 4 + rg;
            if (row >= N_NODES) continue;
#pragma unroll
            for (int j = 0; j < 4; j++) {
                int col = n0 + wn * 64 + j * 16 + r;
                float v = acc[i][j][rg] + bia[j];
                if (mode >= 1) v = fmaxf(v, 0.f);
                if (mode == 2) v = v * sc[j] + sh[j];
                size_t oix = (size_t)row * HIDDEN + col;
                if (Cf) {
                    Cf[oix] = v;
                } else {
                    ushort_t hb = f2b(v);
                    ushort_t lb = f2b(v - b2f(hb));
                    Chi[oix] = hb;
                    Clo[oix] = lb;
                }
            }
        }
    }
}

// ---------------------------------------------------------------------------
// K=64 specialized GEMM: whole K staged once in 64 KB LDS, ONE barrier total.
// ---------------------------------------------------------------------------
__global__ __launch_bounds__(256) void gemm_k64_kernel(
    const ushort_t* __restrict__ Ahi, const ushort_t* __restrict__ Alo,
    const ushort_t* __restrict__ Bhi, const ushort_t* __restrict__ Blo,
    const float* __restrict__ bias,
    ushort_t* __restrict__ Chi, ushort_t* __restrict__ Clo) {
    const int K = 64;
    __shared__ ushort_t As_h[128 * 64];
    __shared__ ushort_t As_l[128 * 64];
    __shared__ ushort_t Bs_h[128 * 64];
    __shared__ ushort_t Bs_l[128 * 64];

    const int tid  = threadIdx.x;
    const int wave = tid >> 6, lane = tid & 63;
    const int wm = wave >> 1, wn = wave & 1;
    const int quad = lane >> 4, r = lane & 15;

    int idx = blockIdx.x, m_t, n_t;
    if (idx < FULLGRP) {
        m_t = (idx >> 5) * 8 + (idx & 7);
        n_t = (idx >> 3) & 3;
    } else {
        int t = idx - FULLGRP;
        m_t = (FULLGRP >> 2) + (t >> 2);
        n_t = t & 3;
    }
    const int m0 = m_t * 128, n0 = n_t * 128;

    const int srow8 = lane >> 3;                       // 0..7
    const int sc8   = (((lane & 7) - srow8) & 7) * 8;  // src elem offset
#pragma unroll
    for (int t = 0; t < 4; t++) {
        int base = wave * 32 + t * 8;
        int rr = base + srow8;
        int lbase = base * 64;
        size_t ga = (size_t)(m0 + rr) * K + sc8;
        size_t gb = (size_t)(n0 + rr) * K + sc8;
        async_copy16(Ahi + ga, &As_h[lbase]);
        async_copy16(Alo + ga, &As_l[lbase]);
        async_copy16(Bhi + gb, &Bs_h[lbase]);
        async_copy16(Blo + gb, &Bs_l[lbase]);
    }
    __syncthreads();

    const f32x4 vzero = {0.f, 0.f, 0.f, 0.f};
    f32x4 acc[4][4];
#pragma unroll
    for (int i = 0; i < 4; i++)
#pragma unroll
        for (int j = 0; j < 4; j++) acc[i][j] = vzero;

#pragma unroll
    for (int ks = 0; ks < 2; ks++) {
        bf16x8 ah[4], al[4], bh[4], bl[4];
#pragma unroll
        for (int i = 0; i < 4; i++) {
            int ra = wm * 64 + i * 16 + r;
            int rb = wn * 64 + i * 16 + r;
            int ca = ((quad + ks * 4 + (ra & 7)) & 7) * 8;
            int cb = ((quad + ks * 4 + (rb & 7)) & 7) * 8;
            ah[i] = *(const bf16x8*)&As_h[ra * 64 + ca];
            al[i] = *(const bf16x8*)&As_l[ra * 64 + ca];
            bh[i] = *(const bf16x8*)&Bs_h[rb * 64 + cb];
            bl[i] = *(const bf16x8*)&Bs_l[rb * 64 + cb];
        }
#pragma unroll
        for (int i = 0; i < 4; i++)
#pragma unroll
            for (int j = 0; j < 4; j++) {
                acc[i][j] = __builtin_amdgcn_mfma_f32_16x16x32_bf16(ah[i], bh[j], acc[i][j], 0, 0, 0);
                acc[i][j] = __builtin_amdgcn_mfma_f32_16x16x32_bf16(ah[i], bl[j], acc[i][j], 0, 0, 0);
                acc[i][j] = __builtin_amdgcn_mfma_f32_16x16x32_bf16(al[i], bh[j], acc[i][j], 0, 0, 0);
            }
    }

    float bia[4];
#pragma unroll
    for (int j = 0; j < 4; j++) bia[j] = bias[n0 + wn * 64 + j * 16 + r];
#pragma unroll
    for (int i = 0; i < 4; i++) {
#pragma unroll
        for (int rg = 0; rg < 4; rg++) {
            int row = m0 + wm * 64 + i * 16 + quad * 4 + rg;
            if (row >= N_NODES) continue;
#pragma unroll
            for (int j = 0; j < 4; j++) {
                int col = n0 + wn * 64 + j * 16 + r;
                float v = fmaxf(acc[i][j][rg] + bia[j], 0.f);
                size_t oix = (size_t)row * HIDDEN + col;
                ushort_t hb = f2b(v);
                ushort_t lb = f2b(v - b2f(hb));
                Chi[oix] = hb;
                Clo[oix] = lb;
            }
        }
    }
}

// ---------------------------------------------------------------------------
// out[t] = (h[a_t] * h[b_t]) @ fc2_W + fc2_b ; one wave per train edge.
// ---------------------------------------------------------------------------
__global__ __launch_bounds__(256) void fc2_kernel(
    const float* __restrict__ h, const int* __restrict__ ei,
    const int* __restrict__ teid, const float* __restrict__ W,
    const float* __restrict__ bias, float* __restrict__ out) {
    __shared__ float Ws[HIDDEN * N_CLASS];
    __shared__ float bs[N_CLASS];
    for (int i = threadIdx.x; i < HIDDEN * N_CLASS; i += blockDim.x) Ws[i] = W[i];
    if (threadIdx.x < N_CLASS) bs[threadIdx.x] = bias[threadIdx.x];
    __syncthreads();

    int wave = threadIdx.x >> 6;
    int lane = threadIdx.x & 63;
    int t = blockIdx.x * 4 + wave;
    if (t >= N_TRAIN) return;

    int e = teid[t];
    int a = ei[e];
    int b = ei[N_EDGES + e];
    const float* xa = h + (size_t)a * HIDDEN;
    const float* xb = h + (size_t)b * HIDDEN;

    float acc[N_CLASS];
#pragma unroll
    for (int c = 0; c < N_CLASS; c++) acc[c] = 0.f;

    int j0 = lane * 8;
    float4 a0 = *(const float4*)&xa[j0];
    float4 a1 = *(const float4*)&xa[j0 + 4];
    float4 b0 = *(const float4*)&xb[j0];
    float4 b1 = *(const float4*)&xb[j0 + 4];
    float p[8] = {a0.x * b0.x, a0.y * b0.y, a0.z * b0.z, a0.w * b0.w,
                  a1.x * b1.x, a1.y * b1.y, a1.z * b1.z, a1.w * b1.w};
#pragma unroll
    for (int jj = 0; jj < 8; jj++) {
        const float* wrow = &Ws[(j0 + jj) * N_CLASS];
#pragma unroll
        for (int c = 0; c < N_CLASS; c++) acc[c] = fmaf(p[jj], wrow[c], acc[c]);
    }
#pragma unroll
    for (int c = 0; c < N_CLASS; c++) {
        float v = acc[c];
        for (int off = 32; off > 0; off >>= 1) v += __shfl_down(v, off, 64);
        if (lane == 0) out[(size_t)t * N_CLASS + c] = v + bs[c];
    }
}

// ---------------------------------------------------------------------------
extern "C" void kernel_launch(void* const* d_in, const int* in_sizes, int n_in,
                              void* d_out, int out_size, void* d_ws, size_t ws_size,
                              hipStream_t stream) {
    const float* x      = (const float*)d_in[0];
    const int*   ei     = (const int*)d_in[1];
    const int*   teid   = (const int*)d_in[2];
    const float* W1     = (const float*)d_in[3];
    const float* b1     = (const float*)d_in[4];
    const float* W2     = (const float*)d_in[5];
    const float* b2     = (const float*)d_in[6];
    const float* W3     = (const float*)d_in[7];
    const float* b3     = (const float*)d_in[8];
    const float* bn1_g  = (const float*)d_in[9];
    const float* bn1_b  = (const float*)d_in[10];
    const float* bn1_m  = (const float*)d_in[11];
    const float* bn1_v  = (const float*)d_in[12];
    const float* eps1   = (const float*)d_in[13];
    const float* W4     = (const float*)d_in[14];
    const float* b4     = (const float*)d_in[15];
    const float* bn2_g  = (const float*)d_in[16];
    const float* bn2_b  = (const float*)d_in[17];
    const float* bn2_m  = (const float*)d_in[18];
    const float* bn2_v  = (const float*)d_in[19];
    const float* eps2   = (const float*)d_in[20];
    const float* lin1_W = (const float*)d_in[21];
    const float* lin1_b = (const float*)d_in[22];
    const float* lin2_W = (const float*)d_in[23];
    const float* lin2_b = (const float*)d_in[24];
    const float* fc2_W  = (const float*)d_in[25];
    const float* fc2_b  = (const float*)d_in[26];

    const size_t PLANE   = (size_t)MPAD * HIDDEN;
    const size_t PLANE64 = (size_t)MPAD * IN_F;

    ushort_t* R0h = (ushort_t*)d_ws;
    ushort_t* R0l = R0h + PLANE;
    ushort_t* R1h = R0l + PLANE;
    ushort_t* R1l = R1h + PLANE;

    const size_t WSMALL = (size_t)HIDDEN * IN_F;
    const size_t WBIG   = (size_t)HIDDEN * HIDDEN;
    ushort_t* Wp   = R1l + PLANE;
    ushort_t* Wt1h = Wp;            ushort_t* Wt1l = Wt1h + WSMALL;
    ushort_t* Wt2h = Wt1l + WSMALL; ushort_t* Wt2l = Wt2h + WBIG;
    ushort_t* Wt3h = Wt2l + WBIG;   ushort_t* Wt3l = Wt3h + WBIG;
    ushort_t* Wt4h = Wt3l + WBIG;   ushort_t* Wt4l = Wt4h + WBIG;
    ushort_t* Wt5h = Wt4l + WBIG;   ushort_t* Wt5l = Wt5h + WBIG;
    ushort_t* Wt6h = Wt5l + WBIG;   ushort_t* Wt6l = Wt6h + WBIG;

    // CSR arrays (ints) after weights
    int* deg    = (int*)(Wt6l + WBIG);
    int* cursor = deg + N_NODES;
    int* rowptr = cursor + N_NODES;        // N_NODES + 1
    int* bsum   = rowptr + (N_NODES + 1);  // NBLK
    int* boff   = bsum + NBLK;             // NBLK
    int* adj    = boff + NBLK;             // N_EDGES

    // fp32 aliases
    float* F32_R0 = (float*)R0h;
    ushort_t* H0h = R1h;
    ushort_t* H0l = R1h + PLANE64;

    // ---- CSR build (decoupled scan) ----
    zero_kernel<<<(N_NODES + 255) / 256, 256, 0, stream>>>(deg, N_NODES);
    hist_kernel<<<(N_EDGES + 255) / 256, 256, 0, stream>>>(ei, deg);
    blocksum_kernel<<<NBLK, 256, 0, stream>>>(deg, bsum);
    scanbsum_kernel<<<1, 256, 0, stream>>>(bsum, boff);
    rowptr_kernel<<<NBLK, 256, 0, stream>>>(deg, boff, rowptr, cursor);
    scatter_kernel<<<(N_EDGES + 255) / 256, 256, 0, stream>>>(ei, cursor, adj);

    // ---- weight prep: one batched launch ----
    wtrans_all_kernel<<<dim3(16, 16, 6), 256, 0, stream>>>(W1, W2, W3, W4,
                                                           lin1_W, lin2_W, Wp);

    const int ngrid = MT * NT;     // 1564 blocks, 1-D swizzled grid
    int nwb = (N_NODES + 3) / 4;

    // ---- h0 = (1+eps1)*x + gather(x) -> H0 split ----
    gather64_kernel<<<nwb, 256, 0, stream>>>(x, rowptr, adj, eps1, H0h, H0l);

    // h1 = relu(h0 @ W1 + b1) -> R0 split  (K=64 single-stage kernel)
    gemm_k64_kernel<<<ngrid, 256, 0, stream>>>(H0h, H0l, Wt1h, Wt1l, b1, R0h, R0l);
    // h2 = relu(h1 @ W2 + b2) -> R1 split
    gemm_split_kernel<HIDDEN><<<ngrid, 256, 0, stream>>>(R0h, R0l, Wt2h, Wt2l, b2,
        nullptr, R1h, R1l, 1, nullptr, nullptr, nullptr, nullptr);
    // h3 = bn1(relu(h2 @ W3 + b3)) -> F32_R0
    gemm_split_kernel<HIDDEN><<<ngrid, 256, 0, stream>>>(R1h, R1l, Wt3h, Wt3l, b3,
        F32_R0, nullptr, nullptr, 2, bn1_g, bn1_b, bn1_m, bn1_v);

    // ---- h4 = (1+eps2)*h3 + gather(h3) -> R1 split (2 waves/node) ----
    gather512_kernel<<<(N_NODES + 1) / 2, 256, 0, stream>>>(F32_R0, rowptr, adj,
                                                            eps2, R1h, R1l);

    // h5 = bn2(relu(h4 @ W4 + b4)) -> R0 split
    gemm_split_kernel<HIDDEN><<<ngrid, 256, 0, stream>>>(R1h, R1l, Wt4h, Wt4l, b4,
        nullptr, R0h, R0l, 2, bn2_g, bn2_b, bn2_m, bn2_v);
    // h6 = relu(h5 @ lin1_W + lin1_b) -> R1 split
    gemm_split_kernel<HIDDEN><<<ngrid, 256, 0, stream>>>(R0h, R0l, Wt5h, Wt5l, lin1_b,
        nullptr, R1h, R1l, 1, nullptr, nullptr, nullptr, nullptr);
    // h7 = h6 @ lin2_W + lin2_b -> F32_R0
    gemm_split_kernel<HIDDEN><<<ngrid, 256, 0, stream>>>(R1h, R1l, Wt6h, Wt6l, lin2_b,
        F32_R0, nullptr, nullptr, 0, nullptr, nullptr, nullptr, nullptr);

    // head
    fc2_kernel<<<(N_TRAIN + 3) / 4, 256, 0, stream>>>(F32_R0, ei, teid, fc2_W, fc2_b,
                                                      (float*)d_out);
}

// Round 12
// 925.429 us; speedup vs baseline: 1.5449x; 1.0359x over previous
//
#include <hip/hip_runtime.h>

#define N_NODES 50000
#define MPAD    50048           // N_NODES rounded up to 128
#define IN_F    64
#define HIDDEN  512
#define N_EDGES 160000
#define N_TRAIN 80000
#define N_CLASS 7
#define BN_EPS  1e-5f

#define MT      (MPAD / 128)    // 391 m-tiles
#define NT      4               // 128-col n-tiles
#define NTILE   (MT * NT)       // 1564 tiles
// 3 blocks/CU (96 VGPR + 64 AGPR = 160/wave -> 3 waves/SIMD) -> 768 slots.
// 1564 = 768*2 + 28: a 28-block third occupancy-wave wastes a full T_b.
// Fold to 1536 workers: blocks 0..27 do 2 tiles (dispatched first -> long
// poles start early); makespan ~2.04*T_b instead of 3*T_b.
#define GGRID   1536
#define FULLGRP ((MT / 8) * 32) // 1536: full 8-mtile x 4-ntile swizzle groups
#define NBLK    ((N_NODES + 255) / 256)   // 196 scan blocks

typedef short  bf16x8 __attribute__((ext_vector_type(8)));
typedef float  f32x4  __attribute__((ext_vector_type(4)));
typedef unsigned short ushort_t;

// ---- bf16 helpers (manual RNE; values are finite) -------------------------
__device__ __forceinline__ ushort_t f2b(float v) {
    union { float f; unsigned int u; } c; c.f = v;
    unsigned int x = c.u;
    unsigned int r = (x + 0x7FFFu + ((x >> 16) & 1u)) >> 16;
    return (ushort_t)r;
}
__device__ __forceinline__ float b2f(ushort_t b) {
    union { unsigned int u; float f; } c; c.u = ((unsigned int)b) << 16;
    return c.f;
}

// ---- async global->LDS, 16B per lane (dst = wave-uniform base + lane*16) --
__device__ __forceinline__ void async_copy16(const void* g, void* l) {
    __builtin_amdgcn_global_load_lds(
        (const __attribute__((address_space(1))) void*)g,
        (__attribute__((address_space(3))) void*)l, 16, 0, 0);
}

// ---- swizzled tile index -> (m0, n0) --------------------------------------
__device__ __forceinline__ void tile_map(int idx, int& m0, int& n0) {
    int m_t, n_t;
    if (idx < FULLGRP) {
        m_t = (idx >> 5) * 8 + (idx & 7);
        n_t = (idx >> 3) & 3;
    } else {
        int t = idx - FULLGRP;
        m_t = (FULLGRP >> 2) + (t >> 2);
        n_t = t & 3;
    }
    m0 = m_t * 128; n0 = n_t * 128;
}

// ===========================================================================
// CSR build: zero -> histogram(dst) -> decoupled scan -> scatter src ids.
// Separate small launches: R10 showed grid.sync() costs ~80 µs/sync on this
// stack — a chain of tiny ordinary launches is an order of magnitude cheaper.
// ===========================================================================
__global__ void zero_kernel(int* __restrict__ p, int n) {
    int i = blockIdx.x * blockDim.x + threadIdx.x;
    if (i < n) p[i] = 0;
}

__global__ void hist_kernel(const int* __restrict__ ei, int* __restrict__ deg) {
    int e = blockIdx.x * blockDim.x + threadIdx.x;
    if (e >= N_EDGES) return;
    atomicAdd(&deg[ei[N_EDGES + e]], 1);
}

// per-256-chunk sums of deg
__global__ __launch_bounds__(256) void blocksum_kernel(const int* __restrict__ deg,
                                                       int* __restrict__ bsum) {
    __shared__ int s[256];
    int i = blockIdx.x * 256 + threadIdx.x;
    s[threadIdx.x] = (i < N_NODES) ? deg[i] : 0;
    __syncthreads();
    for (int off = 128; off > 0; off >>= 1) {
        if (threadIdx.x < off) s[threadIdx.x] += s[threadIdx.x + off];
        __syncthreads();
    }
    if (threadIdx.x == 0) bsum[blockIdx.x] = s[0];
}

// single block: exclusive scan of NBLK(=196) block sums
__global__ __launch_bounds__(256) void scanbsum_kernel(const int* __restrict__ bsum,
                                                       int* __restrict__ boff) {
    __shared__ int s[256];
    int tid = threadIdx.x;
    s[tid] = (tid < NBLK) ? bsum[tid] : 0;
    __syncthreads();
    for (int off = 1; off < 256; off <<= 1) {
        int t = (tid >= off) ? s[tid - off] : 0;
        __syncthreads();
        s[tid] += t;
        __syncthreads();
    }
    if (tid < NBLK) boff[tid] = (tid == 0) ? 0 : s[tid - 1];
}

// per-block local inclusive scan + block offset -> rowptr and scatter cursor
__global__ __launch_bounds__(256) void rowptr_kernel(const int* __restrict__ deg,
                                                     const int* __restrict__ boff,
                                                     int* __restrict__ rowptr,
                                                     int* __restrict__ cursor) {
    __shared__ int s[256];
    int tid = threadIdx.x;
    int i = blockIdx.x * 256 + tid;
    int d = (i < N_NODES) ? deg[i] : 0;
    s[tid] = d;
    __syncthreads();
    for (int off = 1; off < 256; off <<= 1) {
        int t = (tid >= off) ? s[tid - off] : 0;
        __syncthreads();
        s[tid] += t;
        __syncthreads();
    }
    int incl = s[tid] + boff[blockIdx.x];
    if (i < N_NODES) {
        rowptr[i + 1] = incl;
        cursor[i] = incl - d;   // exclusive prefix = row start
    }
    if (i == 0) rowptr[0] = 0;
}

__global__ void scatter_kernel(const int* __restrict__ ei,
                               int* __restrict__ cursor, int* __restrict__ adj) {
    int e = blockIdx.x * blockDim.x + threadIdx.x;
    if (e >= N_EDGES) return;
    int src = ei[e], dst = ei[N_EDGES + e];
    int pos = atomicAdd(&cursor[dst], 1);
    adj[pos] = src;
}

// ===========================================================================
// Gather aggregation (CSR), fused scale + split-bf16 output.
// out[n] = (1+eps)*h[n] + sum_{k in row n} h[adj[k]]
// ===========================================================================
__global__ __launch_bounds__(256) void gather64_kernel(
    const float* __restrict__ x, const int* __restrict__ rowptr,
    const int* __restrict__ adj, const float* __restrict__ epsp,
    ushort_t* __restrict__ hi, ushort_t* __restrict__ lo) {
    int wave = threadIdx.x >> 6, lane = threadIdx.x & 63;
    int n = blockIdx.x * 4 + wave;
    if (n >= N_NODES) return;
    float s = 1.0f + *epsp;
    float sum = s * x[(size_t)n * IN_F + lane];
    int beg = rowptr[n], end = rowptr[n + 1];
    for (int k = beg; k < end; k++) {
        sum += x[(size_t)adj[k] * IN_F + lane];
    }
    ushort_t hb = f2b(sum);
    ushort_t lb = f2b(sum - b2f(hb));
    hi[(size_t)n * IN_F + lane] = hb;
    lo[(size_t)n * IN_F + lane] = lb;
}

// 2 waves per node (256 features each)
__global__ __launch_bounds__(256) void gather512_kernel(
    const float* __restrict__ h, const int* __restrict__ rowptr,
    const int* __restrict__ adj, const float* __restrict__ epsp,
    ushort_t* __restrict__ hi, ushort_t* __restrict__ lo) {
    int wave = threadIdx.x >> 6, lane = threadIdx.x & 63;
    int n = blockIdx.x * 2 + (wave >> 1);
    if (n >= N_NODES) return;
    float s = 1.0f + *epsp;
    const int f = (wave & 1) * 256 + lane * 4;
    float4 a = *(const float4*)&h[(size_t)n * HIDDEN + f];
    float sum[4] = {s * a.x, s * a.y, s * a.z, s * a.w};
    int beg = rowptr[n], end = rowptr[n + 1];
    for (int k = beg; k < end; k++) {
        float4 b = *(const float4*)&h[(size_t)adj[k] * HIDDEN + f];
        sum[0] += b.x; sum[1] += b.y; sum[2] += b.z; sum[3] += b.w;
    }
    ushort_t h4[4], l4[4];
#pragma unroll
    for (int j = 0; j < 4; j++) {
        h4[j] = f2b(sum[j]);
        l4[j] = f2b(sum[j] - b2f(h4[j]));
    }
    *(ushort4*)&hi[(size_t)n * HIDDEN + f] = make_ushort4(h4[0], h4[1], h4[2], h4[3]);
    *(ushort4*)&lo[(size_t)n * HIDDEN + f] = make_ushort4(l4[0], l4[1], l4[2], l4[3]);
}

// ---------------------------------------------------------------------------
// Batched weight prep: all 6 W[K][512] fp32 -> Wt_hi/lo[512][K] bf16.
// grid (16, 16, 6); z selects weight; z=0 has K=64 (extra kb blocks exit).
// ---------------------------------------------------------------------------
__global__ void wtrans_all_kernel(const float* __restrict__ w0,
                                  const float* __restrict__ w1,
                                  const float* __restrict__ w2,
                                  const float* __restrict__ w3,
                                  const float* __restrict__ w4,
                                  const float* __restrict__ w5,
                                  ushort_t* __restrict__ Wp) {
    const size_t WSMALL = (size_t)HIDDEN * IN_F;
    const size_t WBIG   = (size_t)HIDDEN * HIDDEN;
    int z = blockIdx.z;
    const float* W = (z == 0) ? w0 : (z == 1) ? w1 : (z == 2) ? w2
                   : (z == 3) ? w3 : (z == 4) ? w4 : w5;
    int K = (z == 0) ? IN_F : HIDDEN;
    size_t off_h = (z == 0) ? 0 : 2 * WSMALL + (size_t)(z - 1) * 2 * WBIG;
    ushort_t* Whi = Wp + off_h;
    ushort_t* Wlo = Whi + ((z == 0) ? WSMALL : WBIG);

    __shared__ float t[32][33];
    int tx = threadIdx.x & 31, ty = threadIdx.x >> 5;   // ty 0..7
    int nb = blockIdx.x * 32, kb = blockIdx.y * 32;
    if (kb >= K) return;
#pragma unroll
    for (int i = 0; i < 4; i++) {
        int k = kb + ty + i * 8;
        t[ty + i * 8][tx] = W[(size_t)k * HIDDEN + nb + tx];
    }
    __syncthreads();
#pragma unroll
    for (int i = 0; i < 4; i++) {
        int n = nb + ty + i * 8;
        int k = kb + tx;
        float v = t[tx][ty + i * 8];
        ushort_t hb = f2b(v);
        ushort_t lb = f2b(v - b2f(hb));
        Whi[(size_t)n * K + k] = hb;
        Wlo[(size_t)n * K + k] = lb;
    }
}

// ---------------------------------------------------------------------------
// Split-bf16 MFMA GEMM (K=512): single-buffer LDS + verified swizzle.
// Internal structure FROZEN (R5-R8). NEW: grid folded to GGRID workers so
// tile count packs into exactly ~2 occupancy waves (see GGRID comment).
// ---------------------------------------------------------------------------
template<int K>
__global__ __launch_bounds__(256) void gemm_split_kernel(
    const ushort_t* __restrict__ Ahi, const ushort_t* __restrict__ Alo,
    const ushort_t* __restrict__ Bhi, const ushort_t* __restrict__ Blo,
    const float* __restrict__ bias,
    float* __restrict__ Cf, ushort_t* __restrict__ Chi, ushort_t* __restrict__ Clo,
    int mode,
    const float* __restrict__ bn_g, const float* __restrict__ bn_b,
    const float* __restrict__ bn_m, const float* __restrict__ bn_v) {
    __shared__ ushort_t As_h[128 * 32];
    __shared__ ushort_t As_l[128 * 32];
    __shared__ ushort_t Bs_h[128 * 32];
    __shared__ ushort_t Bs_l[128 * 32];

    const int tid  = threadIdx.x;
    const int wave = tid >> 6, lane = tid & 63;
    const int wm = wave >> 1, wn = wave & 1;
    const int quad = lane >> 4, r = lane & 15;

    const int srow = lane >> 2;
    const int scol = (((lane & 3) + ((srow >> 1) & 3)) & 3) * 8;
    const int csw  = ((quad - ((r >> 1) & 3)) & 3) * 8;

    for (int tile = blockIdx.x; tile < NTILE; tile += GGRID) {
        int m0, n0;
        tile_map(tile, m0, n0);

        const f32x4 vzero = {0.f, 0.f, 0.f, 0.f};
        f32x4 acc[4][4];
#pragma unroll
        for (int i = 0; i < 4; i++)
#pragma unroll
            for (int j = 0; j < 4; j++) acc[i][j] = vzero;

        for (int k0 = 0; k0 < K; k0 += 32) {
            __syncthreads();
#pragma unroll
            for (int tt = 0; tt < 2; tt++) {
                int rr = wave * 32 + tt * 16 + srow;
                int lbase = (wave * 32 + tt * 16) * 32;
                size_t ga = (size_t)(m0 + rr) * K + k0 + scol;
                size_t gb = (size_t)(n0 + rr) * K + k0 + scol;
                async_copy16(Ahi + ga, &As_h[lbase]);
                async_copy16(Alo + ga, &As_l[lbase]);
                async_copy16(Bhi + gb, &Bs_h[lbase]);
                async_copy16(Blo + gb, &Bs_l[lbase]);
            }
            __syncthreads();

            bf16x8 ah[4], al[4], bh[4], bl[4];
#pragma unroll
            for (int i = 0; i < 4; i++) {
                int aofs = (wm * 64 + i * 16 + r) * 32 + csw;
                int bofs = (wn * 64 + i * 16 + r) * 32 + csw;
                ah[i] = *(const bf16x8*)&As_h[aofs];
                al[i] = *(const bf16x8*)&As_l[aofs];
                bh[i] = *(const bf16x8*)&Bs_h[bofs];
                bl[i] = *(const bf16x8*)&Bs_l[bofs];
            }
#pragma unroll
            for (int i = 0; i < 4; i++)
#pragma unroll
                for (int j = 0; j < 4; j++) {
                    acc[i][j] = __builtin_amdgcn_mfma_f32_16x16x32_bf16(ah[i], bh[j], acc[i][j], 0, 0, 0);
                    acc[i][j] = __builtin_amdgcn_mfma_f32_16x16x32_bf16(ah[i], bl[j], acc[i][j], 0, 0, 0);
                    acc[i][j] = __builtin_amdgcn_mfma_f32_16x16x32_bf16(al[i], bh[j], acc[i][j], 0, 0, 0);
                }
        }

        float bia[4], sc[4], sh[4];
#pragma unroll
        for (int j = 0; j < 4; j++) {
            int col = n0 + wn * 64 + j * 16 + r;
            bia[j] = bias[col];
            if (mode == 2) {
                float g = bn_g[col], bb = bn_b[col], mm = bn_m[col], vv = bn_v[col];
                sc[j] = g * rsqrtf(vv + BN_EPS);
                sh[j] = bb - mm * sc[j];
            } else { sc[j] = 1.f; sh[j] = 0.f; }
        }
#pragma unroll
        for (int i = 0; i < 4; i++) {
#pragma unroll
            for (int rg = 0; rg < 4; rg++) {
                int row = m0 + wm * 64 + i * 16 + quad * 4 + rg;
                if (row >= N_NODES) continue;
#pragma unroll
                for (int j = 0; j < 4; j++) {
                    int col = n0 + wn * 64 + j * 16 + r;
                    float v = acc[i][j][rg] + bia[j];
                    if (mode >= 1) v = fmaxf(v, 0.f);
                    if (mode == 2) v = v * sc[j] + sh[j];
                    size_t oix = (size_t)row * HIDDEN + col;
                    if (Cf) {
                        Cf[oix] = v;
                    } else {
                        ushort_t hb = f2b(v);
                        ushort_t lb = f2b(v - b2f(hb));
                        Chi[oix] = hb;
                        Clo[oix] = lb;
                    }
                }
            }
        }
        __syncthreads();   // protect LDS before next tile's staging
    }
}

// ---------------------------------------------------------------------------
// K=64 specialized GEMM: whole K staged once in 64 KB LDS, ONE barrier/tile.
// 64 KB LDS -> 2 blocks/CU -> 512 slots; 1564 = 3*512 + 28 -> folding to
// GGRID(=1536) gives exactly 3 clean occupancy waves (was 4).
// ---------------------------------------------------------------------------
__global__ __launch_bounds__(256) void gemm_k64_kernel(
    const ushort_t* __restrict__ Ahi, const ushort_t* __restrict__ Alo,
    const ushort_t* __restrict__ Bhi, const ushort_t* __restrict__ Blo,
    const float* __restrict__ bias,
    ushort_t* __restrict__ Chi, ushort_t* __restrict__ Clo) {
    const int K = 64;
    __shared__ ushort_t As_h[128 * 64];
    __shared__ ushort_t As_l[128 * 64];
    __shared__ ushort_t Bs_h[128 * 64];
    __shared__ ushort_t Bs_l[128 * 64];

    const int tid  = threadIdx.x;
    const int wave = tid >> 6, lane = tid & 63;
    const int wm = wave >> 1, wn = wave & 1;
    const int quad = lane >> 4, r = lane & 15;

    const int srow8 = lane >> 3;                       // 0..7
    const int sc8   = (((lane & 7) - srow8) & 7) * 8;  // src elem offset

    for (int tile = blockIdx.x; tile < NTILE; tile += GGRID) {
        int m0, n0;
        tile_map(tile, m0, n0);

#pragma unroll
        for (int t = 0; t < 4; t++) {
            int base = wave * 32 + t * 8;
            int rr = base + srow8;
            int lbase = base * 64;
            size_t ga = (size_t)(m0 + rr) * K + sc8;
            size_t gb = (size_t)(n0 + rr) * K + sc8;
            async_copy16(Ahi + ga, &As_h[lbase]);
            async_copy16(Alo + ga, &As_l[lbase]);
            async_copy16(Bhi + gb, &Bs_h[lbase]);
            async_copy16(Blo + gb, &Bs_l[lbase]);
        }
        __syncthreads();   // drain DMA, then compute

        const f32x4 vzero = {0.f, 0.f, 0.f, 0.f};
        f32x4 acc[4][4];
#pragma unroll
        for (int i = 0; i < 4; i++)
#pragma unroll
            for (int j = 0; j < 4; j++) acc[i][j] = vzero;

#pragma unroll
        for (int ks = 0; ks < 2; ks++) {
            bf16x8 ah[4], al[4], bh[4], bl[4];
#pragma unroll
            for (int i = 0; i < 4; i++) {
                int ra = wm * 64 + i * 16 + r;
                int rb = wn * 64 + i * 16 + r;
                int ca = ((quad + ks * 4 + (ra & 7)) & 7) * 8;
                int cb = ((quad + ks * 4 + (rb & 7)) & 7) * 8;
                ah[i] = *(const bf16x8*)&As_h[ra * 64 + ca];
                al[i] = *(const bf16x8*)&As_l[ra * 64 + ca];
                bh[i] = *(const bf16x8*)&Bs_h[rb * 64 + cb];
                bl[i] = *(const bf16x8*)&Bs_l[rb * 64 + cb];
            }
#pragma unroll
            for (int i = 0; i < 4; i++)
#pragma unroll
                for (int j = 0; j < 4; j++) {
                    acc[i][j] = __builtin_amdgcn_mfma_f32_16x16x32_bf16(ah[i], bh[j], acc[i][j], 0, 0, 0);
                    acc[i][j] = __builtin_amdgcn_mfma_f32_16x16x32_bf16(ah[i], bl[j], acc[i][j], 0, 0, 0);
                    acc[i][j] = __builtin_amdgcn_mfma_f32_16x16x32_bf16(al[i], bh[j], acc[i][j], 0, 0, 0);
                }
        }

        float bia[4];
#pragma unroll
        for (int j = 0; j < 4; j++) bia[j] = bias[n0 + wn * 64 + j * 16 + r];
#pragma unroll
        for (int i = 0; i < 4; i++) {
#pragma unroll
            for (int rg = 0; rg < 4; rg++) {
                int row = m0 + wm * 64 + i * 16 + quad * 4 + rg;
                if (row >= N_NODES) continue;
#pragma unroll
                for (int j = 0; j < 4; j++) {
                    int col = n0 + wn * 64 + j * 16 + r;
                    float v = fmaxf(acc[i][j][rg] + bia[j], 0.f);
                    size_t oix = (size_t)row * HIDDEN + col;
                    ushort_t hb = f2b(v);
                    ushort_t lb = f2b(v - b2f(hb));
                    Chi[oix] = hb;
                    Clo[oix] = lb;
                }
            }
        }
        __syncthreads();   // protect LDS before next tile's staging
    }
}

// ---------------------------------------------------------------------------
// out[t] = (h[a_t] * h[b_t]) @ fc2_W + fc2_b ; one wave per train edge.
// ---------------------------------------------------------------------------
__global__ __launch_bounds__(256) void fc2_kernel(
    const float* __restrict__ h, const int* __restrict__ ei,
    const int* __restrict__ teid, const float* __restrict__ W,
    const float* __restrict__ bias, float* __restrict__ out) {
    __shared__ float Ws[HIDDEN * N_CLASS];
    __shared__ float bs[N_CLASS];
    for (int i = threadIdx.x; i < HIDDEN * N_CLASS; i += blockDim.x) Ws[i] = W[i];
    if (threadIdx.x < N_CLASS) bs[threadIdx.x] = bias[threadIdx.x];
    __syncthreads();

    int wave = threadIdx.x >> 6;
    int lane = threadIdx.x & 63;
    int t = blockIdx.x * 4 + wave;
    if (t >= N_TRAIN) return;

    int e = teid[t];
    int a = ei[e];
    int b = ei[N_EDGES + e];
    const float* xa = h + (size_t)a * HIDDEN;
    const float* xb = h + (size_t)b * HIDDEN;

    float acc[N_CLASS];
#pragma unroll
    for (int c = 0; c < N_CLASS; c++) acc[c] = 0.f;

    int j0 = lane * 8;
    float4 a0 = *(const float4*)&xa[j0];
    float4 a1 = *(const float4*)&xa[j0 + 4];
    float4 b0 = *(const float4*)&xb[j0];
    float4 b1 = *(const float4*)&xb[j0 + 4];
    float p[8] = {a0.x * b0.x, a0.y * b0.y, a0.z * b0.z, a0.w * b0.w,
                  a1.x * b1.x, a1.y * b1.y, a1.z * b1.z, a1.w * b1.w};
#pragma unroll
    for (int jj = 0; jj < 8; jj++) {
        const float* wrow = &Ws[(j0 + jj) * N_CLASS];
#pragma unroll
        for (int c = 0; c < N_CLASS; c++) acc[c] = fmaf(p[jj], wrow[c], acc[c]);
    }
#pragma unroll
    for (int c = 0; c < N_CLASS; c++) {
        float v = acc[c];
        for (int off = 32; off > 0; off >>= 1) v += __shfl_down(v, off, 64);
        if (lane == 0) out[(size_t)t * N_CLASS + c] = v + bs[c];
    }
}

// ---------------------------------------------------------------------------
extern "C" void kernel_launch(void* const* d_in, const int* in_sizes, int n_in,
                              void* d_out, int out_size, void* d_ws, size_t ws_size,
                              hipStream_t stream) {
    const float* x      = (const float*)d_in[0];
    const int*   ei     = (const int*)d_in[1];
    const int*   teid   = (const int*)d_in[2];
    const float* W1     = (const float*)d_in[3];
    const float* b1     = (const float*)d_in[4];
    const float* W2     = (const float*)d_in[5];
    const float* b2     = (const float*)d_in[6];
    const float* W3     = (const float*)d_in[7];
    const float* b3     = (const float*)d_in[8];
    const float* bn1_g  = (const float*)d_in[9];
    const float* bn1_b  = (const float*)d_in[10];
    const float* bn1_m  = (const float*)d_in[11];
    const float* bn1_v  = (const float*)d_in[12];
    const float* eps1   = (const float*)d_in[13];
    const float* W4     = (const float*)d_in[14];
    const float* b4     = (const float*)d_in[15];
    const float* bn2_g  = (const float*)d_in[16];
    const float* bn2_b  = (const float*)d_in[17];
    const float* bn2_m  = (const float*)d_in[18];
    const float* bn2_v  = (const float*)d_in[19];
    const float* eps2   = (const float*)d_in[20];
    const float* lin1_W = (const float*)d_in[21];
    const float* lin1_b = (const float*)d_in[22];
    const float* lin2_W = (const float*)d_in[23];
    const float* lin2_b = (const float*)d_in[24];
    const float* fc2_W  = (const float*)d_in[25];
    const float* fc2_b  = (const float*)d_in[26];

    const size_t PLANE   = (size_t)MPAD * HIDDEN;
    const size_t PLANE64 = (size_t)MPAD * IN_F;

    ushort_t* R0h = (ushort_t*)d_ws;
    ushort_t* R0l = R0h + PLANE;
    ushort_t* R1h = R0l + PLANE;
    ushort_t* R1l = R1h + PLANE;

    const size_t WSMALL = (size_t)HIDDEN * IN_F;
    const size_t WBIG   = (size_t)HIDDEN * HIDDEN;
    ushort_t* Wp   = R1l + PLANE;
    ushort_t* Wt1h = Wp;            ushort_t* Wt1l = Wt1h + WSMALL;
    ushort_t* Wt2h = Wt1l + WSMALL; ushort_t* Wt2l = Wt2h + WBIG;
    ushort_t* Wt3h = Wt2l + WBIG;   ushort_t* Wt3l = Wt3h + WBIG;
    ushort_t* Wt4h = Wt3l + WBIG;   ushort_t* Wt4l = Wt4h + WBIG;
    ushort_t* Wt5h = Wt4l + WBIG;   ushort_t* Wt5l = Wt5h + WBIG;
    ushort_t* Wt6h = Wt5l + WBIG;   ushort_t* Wt6l = Wt6h + WBIG;

    // CSR arrays (ints) after weights
    int* deg    = (int*)(Wt6l + WBIG);
    int* cursor = deg + N_NODES;
    int* rowptr = cursor + N_NODES;        // N_NODES + 1
    int* bsum   = rowptr + (N_NODES + 1);  // NBLK
    int* boff   = bsum + NBLK;             // NBLK
    int* adj    = boff + NBLK;             // N_EDGES

    // fp32 aliases
    float* F32_R0 = (float*)R0h;
    ushort_t* H0h = R1h;
    ushort_t* H0l = R1h + PLANE64;

    // ---- CSR build (decoupled scan) ----
    zero_kernel<<<(N_NODES + 255) / 256, 256, 0, stream>>>(deg, N_NODES);
    hist_kernel<<<(N_EDGES + 255) / 256, 256, 0, stream>>>(ei, deg);
    blocksum_kernel<<<NBLK, 256, 0, stream>>>(deg, bsum);
    scanbsum_kernel<<<1, 256, 0, stream>>>(bsum, boff);
    rowptr_kernel<<<NBLK, 256, 0, stream>>>(deg, boff, rowptr, cursor);
    scatter_kernel<<<(N_EDGES + 255) / 256, 256, 0, stream>>>(ei, cursor, adj);

    // ---- weight prep: one batched launch ----
    wtrans_all_kernel<<<dim3(16, 16, 6), 256, 0, stream>>>(W1, W2, W3, W4,
                                                           lin1_W, lin2_W, Wp);

    int nwb = (N_NODES + 3) / 4;

    // ---- h0 = (1+eps1)*x + gather(x) -> H0 split ----
    gather64_kernel<<<nwb, 256, 0, stream>>>(x, rowptr, adj, eps1, H0h, H0l);

    // h1 = relu(h0 @ W1 + b1) -> R0 split  (K=64 single-stage kernel)
    gemm_k64_kernel<<<GGRID, 256, 0, stream>>>(H0h, H0l, Wt1h, Wt1l, b1, R0h, R0l);
    // h2 = relu(h1 @ W2 + b2) -> R1 split
    gemm_split_kernel<HIDDEN><<<GGRID, 256, 0, stream>>>(R0h, R0l, Wt2h, Wt2l, b2,
        nullptr, R1h, R1l, 1, nullptr, nullptr, nullptr, nullptr);
    // h3 = bn1(relu(h2 @ W3 + b3)) -> F32_R0
    gemm_split_kernel<HIDDEN><<<GGRID, 256, 0, stream>>>(R1h, R1l, Wt3h, Wt3l, b3,
        F32_R0, nullptr, nullptr, 2, bn1_g, bn1_b, bn1_m, bn1_v);

    // ---- h4 = (1+eps2)*h3 + gather(h3) -> R1 split (2 waves/node) ----
    gather512_kernel<<<(N_NODES + 1) / 2, 256, 0, stream>>>(F32_R0, rowptr, adj,
                                                            eps2, R1h, R1l);

    // h5 = bn2(relu(h4 @ W4 + b4)) -> R0 split
    gemm_split_kernel<HIDDEN><<<GGRID, 256, 0, stream>>>(R1h, R1l, Wt4h, Wt4l, b4,
        nullptr, R0h, R0l, 2, bn2_g, bn2_b, bn2_m, bn2_v);
    // h6 = relu(h5 @ lin1_W + lin1_b) -> R1 split
    gemm_split_kernel<HIDDEN><<<GGRID, 256, 0, stream>>>(R0h, R0l, Wt5h, Wt5l, lin1_b,
        nullptr, R1h, R1l, 1, nullptr, nullptr, nullptr, nullptr);
    // h7 = h6 @ lin2_W + lin2_b -> F32_R0
    gemm_split_kernel<HIDDEN><<<GGRID, 256, 0, stream>>>(R1h, R1l, Wt6h, Wt6l, lin2_b,
        F32_R0, nullptr, nullptr, 0, nullptr, nullptr, nullptr, nullptr);

    // head
    fc2_kernel<<<(N_TRAIN + 3) / 4, 256, 0, stream>>>(F32_R0, ei, teid, fc2_W, fc2_b,
                                                      (float*)d_out);
}